// Round 12
// baseline (3723.900 us; speedup 1.0000x reference)
//
#include <hip/hip_runtime.h>

#define BB 256
#define TT 2048
#define HD 100

typedef _Float16 h2v __attribute__((ext_vector_type(2)));

__device__ __forceinline__ float fdot2(unsigned w, unsigned h, float c) {
#if __has_builtin(__builtin_amdgcn_fdot2)
    return __builtin_amdgcn_fdot2(__builtin_bit_cast(h2v, w),
                                  __builtin_bit_cast(h2v, h), c, false);
#else
    h2v a = __builtin_bit_cast(h2v, w), b = __builtin_bit_cast(h2v, h);
    c = fmaf((float)a[0], (float)b[0], c);
    c = fmaf((float)a[1], (float)b[1], c);
    return c;
#endif
}
__device__ __forceinline__ unsigned packh2(float a, float b) {
    h2v p; p[0] = (_Float16)a; p[1] = (_Float16)b;
    return __builtin_bit_cast(unsigned, p);
}
__device__ __forceinline__ float rcp_f(float x) {
#if __has_builtin(__builtin_amdgcn_rcpf)
    return __builtin_amdgcn_rcpf(x);
#else
    return 1.0f / x;
#endif
}
__device__ __forceinline__ float sigmoid_f(float x) { return rcp_f(1.0f + __expf(-x)); }
__device__ __forceinline__ float tanh_f(float x) {
    return fmaf(2.0f, rcp_f(1.0f + __expf(-2.0f * x)), -1.0f);
}

// Pipelined 2-layer LSTM: ONE kernel, grid 512 x 256 threads.
//   blocks 0..255  (role 0): layer 1 on chunk `ch`   (batch row = blockIdx&255)
//   blocks 256..511(role 1): layer 2 on chunk `ch-1`
// h1buf is double-buffered in d_ws; L2 reads the buffer L1 wrote in the
// PREVIOUS LAUNCH (launch-boundary coherence makes this safe; intra-launch
// the two roles touch disjoint buffers). Each CU hosts one L1 + one L2 block
// -> 2 waves/SIMD overlap, while each 256-thread block keeps the R6-verified
// clean register allocation (208 arch VGPRs, no AGPR/scratch tax).
// Per-block structure is verbatim R6 (passed, absmax 4.9e-4):
//  - 200 gate threads x 2 rows, f16x2 weights in registers
//  - branchless gate compute (clamped rows) so every v_readlane source is
//    loaded under full exec (readlane ignores EXEC - R3/R4 lesson)
//  - update/loader roles striped (tid&3) across waves
__global__ __launch_bounds__(256, 1) void lstm_pipe(
    const float* __restrict__ x,
    const float* __restrict__ w_ih1, const float* __restrict__ w_hh1,
    const float* __restrict__ b_ih1, const float* __restrict__ b_hh1,
    const float* __restrict__ w_ih2, const float* __restrict__ w_hh2,
    const float* __restrict__ b_ih2, const float* __restrict__ b_hh2,
    unsigned* __restrict__ h1buf,   // [2][Tc][BB][50] packed f16x2
    float* __restrict__ c1s,        // [BB][HD]
    unsigned* __restrict__ h2sp,    // [BB][50] packed h2 state
    float* __restrict__ c2s,        // [BB][HD]
    float* __restrict__ h2f,        // [BB][HD] final h2 (f32)
    int Tc, int ch, int nch)
{
    const int role = blockIdx.x >> 8;
    const int b    = blockIdx.x & 255;
    const int tid  = threadIdx.x, lane = tid & 63;

    __shared__ unsigned hsp[64];        // h state, packed f16x2 (both roles)
    __shared__ float glds[400];
    __shared__ unsigned xs[2][32][4];   // L1 only

    const bool isG = tid < 200;
    const int  gt  = isG ? tid : 199;   // clamped gate thread id
    const int  um  = tid >> 2;
    const bool isU = ((tid & 3) == 3) && (tid < 200);   // um in 0..49
    const int  g0 = 2 * gt, g1r = 2 * gt + 1;
    const bool tg = (gt >= 100) && (gt < 150);          // rows 200..299 = g gate

    if (role == 0) {
        // ================= LAYER 1: chunk ch =================
        if (ch >= nch) return;
        const int t0 = ch * Tc, first = (ch == 0);
        const size_t bufC = (size_t)(ch & 1) * Tc * BB * 50;        // write buf
        const size_t bufP = (size_t)((ch ^ 1) & 1) * Tc * BB * 50;  // prev buf
        const bool isX = ((tid & 3) == 1) && (tid < 128);           // um in 0..31

        unsigned wA[54], wB[54];
        float bias0, bias1, cc0 = 0.f, cc1 = 0.f;
        { const float4* p = (const float4*)(w_ih1 + (size_t)g0 * 8);
          float4 v0 = p[0], v1 = p[1];
          wA[0] = packh2(v0.x, v0.y); wA[1] = packh2(v0.z, v0.w);
          wA[2] = packh2(v1.x, v1.y); wA[3] = packh2(v1.z, v1.w); }
        { const float4* p = (const float4*)(w_ih1 + (size_t)g1r * 8);
          float4 v0 = p[0], v1 = p[1];
          wB[0] = packh2(v0.x, v0.y); wB[1] = packh2(v0.z, v0.w);
          wB[2] = packh2(v1.x, v1.y); wB[3] = packh2(v1.z, v1.w); }
        { const float4* p = (const float4*)(w_hh1 + (size_t)g0 * HD);
          #pragma unroll
          for (int q = 0; q < 25; ++q) { float4 v = p[q];
              wA[4 + 2*q] = packh2(v.x, v.y); wA[5 + 2*q] = packh2(v.z, v.w); } }
        { const float4* p = (const float4*)(w_hh1 + (size_t)g1r * HD);
          #pragma unroll
          for (int q = 0; q < 25; ++q) { float4 v = p[q];
              wB[4 + 2*q] = packh2(v.x, v.y); wB[5 + 2*q] = packh2(v.z, v.w); } }
        bias0 = b_ih1[g0] + b_hh1[g0];
        bias1 = b_ih1[g1r] + b_hh1[g1r];

        if (isU && !first) {
            cc0 = c1s[b * HD + 2 * um];
            cc1 = c1s[b * HD + 2 * um + 1];
        }
        if (tid < 64) {
            unsigned v = 0u;
            if (!first && tid < 50)
                v = h1buf[bufP + ((size_t)(Tc - 1) * BB + b) * 50 + tid];
            hsp[tid] = v;
        }
        if (isX) {
            const int s = um;
            const float4* p = (const float4*)(x + ((size_t)b * TT + t0 + s) * 8);
            float4 v0 = p[0], v1 = p[1];
            xs[0][s][0] = packh2(v0.x, v0.y); xs[0][s][1] = packh2(v0.z, v0.w);
            xs[0][s][2] = packh2(v1.x, v1.y); xs[0][s][3] = packh2(v1.z, v1.w);
        }
        __syncthreads();

        float4 pa = {0,0,0,0}, pb = {0,0,0,0};
        #pragma unroll 1
        for (int i = 0; i < Tc; ++i) {
            const bool pf = ((i & 31) == 0) && (i + 32 < Tc) && isX;
            if (pf) {
                const float4* p = (const float4*)(x + ((size_t)b * TT + t0 + i + 32 + um) * 8);
                pa = p[0]; pb = p[1];
            }
            const unsigned st = hsp[lane];                 // exec-full load
            const unsigned* xq = xs[(i >> 5) & 1][i & 31];
            unsigned x0 = xq[0], x1 = xq[1], x2 = xq[2], x3 = xq[3];
            float a0 = bias0, a1 = bias1, a2 = 0.f, a3 = 0.f;
            a0 = fdot2(wA[0], x0, a0); a1 = fdot2(wB[0], x0, a1);
            a2 = fdot2(wA[1], x1, a2); a3 = fdot2(wB[1], x1, a3);
            a0 = fdot2(wA[2], x2, a0); a1 = fdot2(wB[2], x2, a1);
            a2 = fdot2(wA[3], x3, a2); a3 = fdot2(wB[3], x3, a3);
            #pragma unroll
            for (int k = 0; k < 50; ++k) {
                unsigned hk = (unsigned)__builtin_amdgcn_readlane((int)st, k);
                if (k & 1) { a2 = fdot2(wA[4 + k], hk, a2); a3 = fdot2(wB[4 + k], hk, a3); }
                else       { a0 = fdot2(wA[4 + k], hk, a0); a1 = fdot2(wB[4 + k], hk, a1); }
            }
            float r0 = a0 + a2, r1 = a1 + a3;
            r0 = tg ? tanh_f(r0) : sigmoid_f(r0);
            r1 = tg ? tanh_f(r1) : sigmoid_f(r1);
            if (isG) *(float2*)(glds + 2 * tid) = make_float2(r0, r1);
            __syncthreads();
            if (isU) {
                const int j = 2 * um;
                float2 gi = *(const float2*)(glds + j);
                float2 gf = *(const float2*)(glds + 100 + j);
                float2 gg = *(const float2*)(glds + 200 + j);
                float2 go = *(const float2*)(glds + 300 + j);
                cc0 = gf.x * cc0 + gi.x * gg.x;
                cc1 = gf.y * cc1 + gi.y * gg.y;
                float h0 = go.x * tanh_f(cc0);
                float h1v = go.y * tanh_f(cc1);
                unsigned hp = packh2(h0, h1v);
                hsp[um] = hp;
                h1buf[bufC + ((size_t)i * BB + b) * 50 + um] = hp;
                if (i == Tc - 1) { c1s[b * HD + j] = cc0; c1s[b * HD + j + 1] = cc1; }
            }
            if (pf) {
                const int nb2 = ((i >> 5) + 1) & 1; const int s = um;
                xs[nb2][s][0] = packh2(pa.x, pa.y); xs[nb2][s][1] = packh2(pa.z, pa.w);
                xs[nb2][s][2] = packh2(pb.x, pb.y); xs[nb2][s][3] = packh2(pb.z, pb.w);
            }
            __syncthreads();
        }
    } else {
        // ================= LAYER 2: chunk ch-1 =================
        if (ch < 1) return;
        const int first = (ch == 1), last = (ch == nch);
        const unsigned* h1rd = h1buf + (size_t)((ch - 1) & 1) * Tc * BB * 50;

        unsigned wIA[50], wIB[50], wHA[50], wHB[50];
        float bias0, bias1, cc0 = 0.f, cc1 = 0.f;
        { const float4* p = (const float4*)(w_ih2 + (size_t)g0 * HD);
          #pragma unroll
          for (int q = 0; q < 25; ++q) { float4 v = p[q];
              wIA[2*q] = packh2(v.x, v.y); wIA[2*q+1] = packh2(v.z, v.w); } }
        { const float4* p = (const float4*)(w_ih2 + (size_t)g1r * HD);
          #pragma unroll
          for (int q = 0; q < 25; ++q) { float4 v = p[q];
              wIB[2*q] = packh2(v.x, v.y); wIB[2*q+1] = packh2(v.z, v.w); } }
        { const float4* p = (const float4*)(w_hh2 + (size_t)g0 * HD);
          #pragma unroll
          for (int q = 0; q < 25; ++q) { float4 v = p[q];
              wHA[2*q] = packh2(v.x, v.y); wHA[2*q+1] = packh2(v.z, v.w); } }
        { const float4* p = (const float4*)(w_hh2 + (size_t)g1r * HD);
          #pragma unroll
          for (int q = 0; q < 25; ++q) { float4 v = p[q];
              wHB[2*q] = packh2(v.x, v.y); wHB[2*q+1] = packh2(v.z, v.w); } }
        bias0 = b_ih2[g0] + b_hh2[g0];
        bias1 = b_ih2[g1r] + b_hh2[g1r];

        if (isU && !first) {
            cc0 = c2s[b * HD + 2 * um];
            cc1 = c2s[b * HD + 2 * um + 1];
        }
        if (tid < 64) {
            unsigned v = 0u;
            if (!first && tid < 50) v = h2sp[b * 50 + tid];
            hsp[tid] = v;
        }
        const int lidx = (lane < 50) ? lane : 49;
        unsigned cur = h1rd[(size_t)b * 50 + lidx];    // step 0 row (all lanes)
        __syncthreads();

        #pragma unroll 1
        for (int i = 0; i < Tc; ++i) {
            const int tn = (i + 1 < Tc) ? (i + 1) : i;
            unsigned nxt = h1rd[((size_t)tn * BB + b) * 50 + lidx];  // all lanes
            const unsigned st2 = hsp[lane];                          // all lanes
            float a0 = bias0, a1 = bias1, a2 = 0.f, a3 = 0.f;
            #pragma unroll
            for (int k = 0; k < 50; ++k) {
                unsigned hk = (unsigned)__builtin_amdgcn_readlane((int)cur, k);
                if (k & 1) { a2 = fdot2(wIA[k], hk, a2); a3 = fdot2(wIB[k], hk, a3); }
                else       { a0 = fdot2(wIA[k], hk, a0); a1 = fdot2(wIB[k], hk, a1); }
            }
            #pragma unroll
            for (int k = 0; k < 50; ++k) {
                unsigned hk = (unsigned)__builtin_amdgcn_readlane((int)st2, k);
                if (k & 1) { a2 = fdot2(wHA[k], hk, a2); a3 = fdot2(wHB[k], hk, a3); }
                else       { a0 = fdot2(wHA[k], hk, a0); a1 = fdot2(wHB[k], hk, a1); }
            }
            float r0 = a0 + a2, r1 = a1 + a3;
            r0 = tg ? tanh_f(r0) : sigmoid_f(r0);
            r1 = tg ? tanh_f(r1) : sigmoid_f(r1);
            if (isG) *(float2*)(glds + 2 * tid) = make_float2(r0, r1);
            __syncthreads();
            if (isU) {
                const int j = 2 * um;
                float2 gi = *(const float2*)(glds + j);
                float2 gf = *(const float2*)(glds + 100 + j);
                float2 gg = *(const float2*)(glds + 200 + j);
                float2 go = *(const float2*)(glds + 300 + j);
                cc0 = gf.x * cc0 + gi.x * gg.x;
                cc1 = gf.y * cc1 + gi.y * gg.y;
                float h0 = go.x * tanh_f(cc0);
                float h1v = go.y * tanh_f(cc1);
                hsp[um] = packh2(h0, h1v);
                if (i == Tc - 1) {
                    h2sp[b * 50 + um] = packh2(h0, h1v);
                    c2s[b * HD + j] = cc0; c2s[b * HD + j + 1] = cc1;
                    if (last) { h2f[b * HD + j] = h0; h2f[b * HD + j + 1] = h1v; }
                }
            }
            __syncthreads();
            cur = nxt;
        }
    }
}

// ---------------- FC head ----------------
__global__ void fc_head(const float* __restrict__ h2,
                        const float* __restrict__ fc1_w, const float* __restrict__ fc1_b,
                        const float* __restrict__ fc2_w, const float* __restrict__ fc2_b,
                        float* __restrict__ out)
{
    const int bidx = threadIdx.x;
    const float* h = h2 + (size_t)bidx * HD;
    float hv[HD];
    #pragma unroll
    for (int kk = 0; kk < HD/4; ++kk) {
        float4 v = *(const float4*)(h + 4*kk);
        hv[4*kk+0]=v.x; hv[4*kk+1]=v.y; hv[4*kk+2]=v.z; hv[4*kk+3]=v.w;
    }
    float y = fc2_b[0];
    #pragma unroll
    for (int m = 0; m < 25; ++m) {
        float a = fc1_b[m];
        const float* wp = fc1_w + m * HD;
        #pragma unroll
        for (int k = 0; k < HD; ++k) a += hv[k] * wp[k];
        y += a * fc2_w[m];
    }
    out[bidx] = y;
}

extern "C" void kernel_launch(void* const* d_in, const int* in_sizes, int n_in,
                              void* d_out, int out_size, void* d_ws, size_t ws_size,
                              hipStream_t stream) {
    const float* x     = (const float*)d_in[0];
    const float* w_ih1 = (const float*)d_in[1];
    const float* w_hh1 = (const float*)d_in[2];
    const float* b_ih1 = (const float*)d_in[3];
    const float* b_hh1 = (const float*)d_in[4];
    const float* w_ih2 = (const float*)d_in[5];
    const float* w_hh2 = (const float*)d_in[6];
    const float* b_ih2 = (const float*)d_in[7];
    const float* b_hh2 = (const float*)d_in[8];
    const float* fc1_w = (const float*)d_in[9];
    const float* fc1_b = (const float*)d_in[10];
    const float* fc2_w = (const float*)d_in[11];
    const float* fc2_b = (const float*)d_in[12];
    float* out = (float*)d_out;

    int Tc = 256;  // multiple of 32, divides TT
    while (Tc > 32 &&
           2 * (size_t)Tc * BB * 50 * 4 + (size_t)BB * (HD * 3 + 50) * 4 > ws_size)
        Tc >>= 1;
    const int nch = TT / Tc;

    unsigned* h1buf = (unsigned*)d_ws;                      // [2][Tc][BB][50]
    float* c1s = (float*)(h1buf + 2 * (size_t)Tc * BB * 50);
    float* c2s = c1s + (size_t)BB * HD;
    float* h2f = c2s + (size_t)BB * HD;
    unsigned* h2sp = (unsigned*)(h2f + (size_t)BB * HD);

    for (int ch = 0; ch <= nch; ++ch) {
        lstm_pipe<<<512, 256, 0, stream>>>(x, w_ih1, w_hh1, b_ih1, b_hh1,
                                           w_ih2, w_hh2, b_ih2, b_hh2,
                                           h1buf, c1s, h2sp, c2s, h2f,
                                           Tc, ch, nch);
    }
    fc_head<<<1, 256, 0, stream>>>(h2f, fc1_w, fc1_b, fc2_w, fc2_b, out);
}